// Round 1
// baseline (1111.046 us; speedup 1.0000x reference)
//
#include <hip/hip_runtime.h>
#include <hip/hip_bf16.h>

// BATPoseDecoder on MI355X (gfx950).
// Shapes: B=4, N=256, M=256, D=524. All inputs/outputs fp32.
// Strategy: split-precision bf16 MFMA (W pre-split hi/lo -> error ~2^-9 only from
// L/h1 rounding; score err sigma ~1.5e-3 vs 3.1%-of-max threshold).
// Kernels: prep (weight fragging into d_ws) -> main (1 wg per (b,n): fused
// MLP GEMMs + softmax + matched + overlap) -> finalize (per-batch Kabsch/SVD/quat).
// R1 changes vs previous session's 1140us kernel (theory: latency/barrier-bound,
// MfmaUtil ~10%):
//  - GEMM1 staged at BK=64 (36 barriers/wg instead of 68; 64 MFMA per drain)
//  - both K-halves' B-frags loaded up front per stage (L2 latency hidden under MFMA)
//  - GEMM2 unroll 2, matched-accum unroll 8
//  - tails parallelized: overlap dot on all 256 threads, shuffle reductions replace
//    t==0 serial 64/128-element LDS sums

#define D_ 524
#define CW_OFF 64
#define OV_OFF 262208   // 64 + 4*256*256

typedef __attribute__((ext_vector_type(8))) short short8;
typedef __attribute__((ext_vector_type(4))) float floatx4;

__device__ __forceinline__ short f2bf(float v) {
  unsigned u = __builtin_bit_cast(unsigned, v);
  unsigned r = (u + 0x7FFFu + ((u >> 16) & 1u)) >> 16;  // RNE, no NaN inputs here
  return (short)(unsigned short)r;
}
__device__ __forceinline__ float bf2f(short s) {
  unsigned u = ((unsigned)(unsigned short)s) << 16;
  return __builtin_bit_cast(float, u);
}

// ---------------- prep: split cw1 (K-padded to 544) and cw2 into hi/lo bf16
// stored directly in MFMA B-fragment order: frag(kk,ct,lane)[i] = W[kk*32+(lane>>4)*8+i][ct*16+(lane&15)]
__global__ void prep_kernel(const float* __restrict__ cw1, const float* __restrict__ cw2,
                            short* __restrict__ w1h, short* __restrict__ w1l,
                            short* __restrict__ w2h, short* __restrict__ w2l) {
  int t = blockIdx.x * 256 + threadIdx.x;
  if (t < 17408) {  // W1: 17 ksteps * 16 coltiles * 64 lanes
    int lane = t & 63, ct = (t >> 6) & 15, kk = t >> 10;
    int col = ct * 16 + (lane & 15);
    int kbase = kk * 32 + ((lane >> 4) << 3);
#pragma unroll
    for (int i = 0; i < 8; ++i) {
      int k = kbase + i;
      float v = (k < D_) ? cw1[k * 256 + col] : 0.f;
      short h = f2bf(v);
      w1h[t * 8 + i] = h;
      w1l[t * 8 + i] = f2bf(v - bf2f(h));
    }
  } else if (t < 21504) {  // W2: 8 ksteps * 8 coltiles * 64 lanes
    int u = t - 17408;
    int lane = u & 63, ct = (u >> 6) & 7, kk = u >> 9;
    int col = ct * 16 + (lane & 15);
    int kbase = kk * 32 + ((lane >> 4) << 3);
#pragma unroll
    for (int i = 0; i < 8; ++i) {
      int k = kbase + i;
      float v = cw2[k * 128 + col];
      short h = f2bf(v);
      w2h[u * 8 + i] = h;
      w2l[u * 8 + i] = f2bf(v - bf2f(h));
    }
  }
}

// ---------------- main: one workgroup per (b,n)
__global__ __launch_bounds__(256, 2) void main_kernel(
    const float* __restrict__ L, const float* __restrict__ tgt,
    const float* __restrict__ cb1, const float* __restrict__ cb2,
    const float* __restrict__ cw3, const float* __restrict__ cb3,
    const float* __restrict__ ow1, const float* __restrict__ ob1,
    const float* __restrict__ ow2, const float* __restrict__ ob2,
    const short8* __restrict__ w1h, const short8* __restrict__ w1l,
    const short8* __restrict__ w2h, const short8* __restrict__ w2l,
    float* __restrict__ out, float* __restrict__ tgtm) {
  int bn = blockIdx.x;
  int b = bn >> 8;
  int t = threadIdx.x;
  int w = t >> 6, lane = t & 63, l15 = lane & 15, q = lane >> 4;

  // LDS ~57 KB -> 2 blocks/CU
  __shared__ __attribute__((aligned(16))) short Ah[2][64 * 72];   // L slab bf16, BK=64, row stride 72
  __shared__ __attribute__((aligned(16))) short h1s[64 * 264];    // h1 bf16, row stride 264
  __shared__ float p_all[256];
  __shared__ float redw[256];
  __shared__ float ovp[256];
  __shared__ float m_s[524];
  __shared__ float o1s[128];
  __shared__ float sS;

  const float* Lbn = L + (size_t)bn * (256 * D_);
  float mac0 = 0.f, mac1 = 0.f, mac2 = 0.f;  // matched accum (d = t, t+256, t+512)

  int srow = t >> 2, sko = (t & 3) * 16;  // staging: thread -> (row, k-offset) of 64x64 slab

#pragma unroll 1
  for (int mt = 0; mt < 4; ++mt) {
    int m0 = mt * 64;
    const float* Lrow = Lbn + (size_t)(m0 + srow) * D_;

    // ---- GEMM1: h1[64x256] = relu(L_tile @ W1 + b1), 2-split MFMA, BK=64 staging
    floatx4 acc[4][4];
#pragma unroll
    for (int r = 0; r < 4; ++r)
#pragma unroll
      for (int c = 0; c < 4; ++c) acc[r][c] = (floatx4)(0.f);

    {  // direct-stage 64-wide slab for stage 0 (k = 0..63)
      floatx4 v0 = *(const floatx4*)(Lrow + sko);
      floatx4 v1 = *(const floatx4*)(Lrow + sko + 4);
      floatx4 v2 = *(const floatx4*)(Lrow + sko + 8);
      floatx4 v3 = *(const floatx4*)(Lrow + sko + 12);
      short8 sv0, sv1;
#pragma unroll
      for (int j = 0; j < 4; ++j) {
        sv0[j] = f2bf(v0[j]); sv0[4 + j] = f2bf(v1[j]);
        sv1[j] = f2bf(v2[j]); sv1[4 + j] = f2bf(v3[j]);
      }
      *(short8*)&Ah[0][srow * 72 + sko] = sv0;
      *(short8*)&Ah[0][srow * 72 + sko + 8] = sv1;
    }
    __syncthreads();

    // stages 0..7: full BK=64 (kk = 2s, 2s+1). stage 8: tail kk=16 only (k 512..543, padded).
#pragma unroll 1
    for (int s = 0; s < 9; ++s) {
      int cb = s & 1;
      // prefetch next slab (k = (s+1)*64 .. +63) into registers
      floatx4 nva, nvb, nvc, nvd;
      if (s < 7) {
        const float* src = Lrow + (s + 1) * 64 + sko;
        nva = *(const floatx4*)(src);
        nvb = *(const floatx4*)(src + 4);
        nvc = *(const floatx4*)(src + 8);
        nvd = *(const floatx4*)(src + 12);
      } else if (s == 7) {  // next slab 512..575 with zero-pad beyond 523
#pragma unroll
        for (int j = 0; j < 4; ++j) {
          int k = 512 + sko + j;
          nva[j] = (k < D_) ? Lrow[k] : 0.f;
          nvb[j] = (k + 4 < D_) ? Lrow[k + 4] : 0.f;
          nvc[j] = (k + 8 < D_) ? Lrow[k + 8] : 0.f;
          nvd[j] = (k + 12 < D_) ? Lrow[k + 12] : 0.f;
        }
      }
      // B-fragments for both K-halves up front (second half's L2 latency hides under MFMA0)
      int kk0 = 2 * s;
      short8 bh0[4], bl0[4], bh1[4], bl1[4];
#pragma unroll
      for (int c = 0; c < 4; ++c) {
        int f = (kk0 * 16 + (w * 4 + c)) * 64 + lane;
        bh0[c] = w1h[f];
        bl0[c] = w1l[f];
      }
      if (s < 8) {
#pragma unroll
        for (int c = 0; c < 4; ++c) {
          int f = ((kk0 + 1) * 16 + (w * 4 + c)) * 64 + lane;
          bh1[c] = w1h[f];
          bl1[c] = w1l[f];
        }
      }
      short8 af[4];
#pragma unroll
      for (int r = 0; r < 4; ++r)
        af[r] = *(const short8*)&Ah[cb][(r * 16 + l15) * 72 + q * 8];
#pragma unroll
      for (int r = 0; r < 4; ++r)
#pragma unroll
        for (int c = 0; c < 4; ++c) {
          acc[r][c] = __builtin_amdgcn_mfma_f32_16x16x32_bf16(af[r], bh0[c], acc[r][c], 0, 0, 0);
          acc[r][c] = __builtin_amdgcn_mfma_f32_16x16x32_bf16(af[r], bl0[c], acc[r][c], 0, 0, 0);
        }
      if (s < 8) {
#pragma unroll
        for (int r = 0; r < 4; ++r)
          af[r] = *(const short8*)&Ah[cb][(r * 16 + l15) * 72 + 32 + q * 8];
#pragma unroll
        for (int r = 0; r < 4; ++r)
#pragma unroll
          for (int c = 0; c < 4; ++c) {
            acc[r][c] = __builtin_amdgcn_mfma_f32_16x16x32_bf16(af[r], bh1[c], acc[r][c], 0, 0, 0);
            acc[r][c] = __builtin_amdgcn_mfma_f32_16x16x32_bf16(af[r], bl1[c], acc[r][c], 0, 0, 0);
          }
        // write prefetched slab into the other buffer
        short8 sv0, sv1;
#pragma unroll
        for (int j = 0; j < 4; ++j) {
          sv0[j] = f2bf(nva[j]); sv0[4 + j] = f2bf(nvb[j]);
          sv1[j] = f2bf(nvc[j]); sv1[4 + j] = f2bf(nvd[j]);
        }
        *(short8*)&Ah[cb ^ 1][srow * 72 + sko] = sv0;
        *(short8*)&Ah[cb ^ 1][srow * 72 + sko + 8] = sv1;
      }
      __syncthreads();
    }

    // epilogue1: bias + relu -> h1s (bf16). D layout: row=(lane>>4)*4+i, col=lane&15.
#pragma unroll
    for (int c = 0; c < 4; ++c) {
      int col = (w * 4 + c) * 16 + l15;
      float b1 = cb1[col];
#pragma unroll
      for (int r = 0; r < 4; ++r)
#pragma unroll
        for (int i = 0; i < 4; ++i) {
          int row = r * 16 + q * 4 + i;
          h1s[row * 264 + col] = f2bf(fmaxf(acc[r][c][i] + b1, 0.f));
        }
    }
    __syncthreads();

    // ---- GEMM2: h2[64x128] = relu(h1 @ W2 + b2); wave owns 2 coltiles x 4 rowtiles
    floatx4 ac2[4][2];
#pragma unroll
    for (int r = 0; r < 4; ++r)
#pragma unroll
      for (int c = 0; c < 2; ++c) ac2[r][c] = (floatx4)(0.f);
#pragma unroll 2
    for (int kk = 0; kk < 8; ++kk) {
      short8 a2[4];
#pragma unroll
      for (int r = 0; r < 4; ++r)
        a2[r] = *(const short8*)&h1s[(r * 16 + l15) * 264 + kk * 32 + q * 8];
      short8 b2h_[2], b2l_[2];
#pragma unroll
      for (int c = 0; c < 2; ++c) {
        int f = (kk * 8 + (w * 2 + c)) * 64 + lane;
        b2h_[c] = w2h[f];
        b2l_[c] = w2l[f];
      }
#pragma unroll
      for (int r = 0; r < 4; ++r)
#pragma unroll
        for (int c = 0; c < 2; ++c) {
          ac2[r][c] = __builtin_amdgcn_mfma_f32_16x16x32_bf16(a2[r], b2h_[c], ac2[r][c], 0, 0, 0);
          ac2[r][c] = __builtin_amdgcn_mfma_f32_16x16x32_bf16(a2[r], b2l_[c], ac2[r][c], 0, 0, 0);
        }
    }

    // ---- GEMM3 + scores: score[m] = sum_c relu(h2+b2)*cw3 + cb3 ; p = exp(score)
    float pr[4][4];
#pragma unroll
    for (int r = 0; r < 4; ++r)
#pragma unroll
      for (int i = 0; i < 4; ++i) pr[r][i] = 0.f;
#pragma unroll
    for (int c = 0; c < 2; ++c) {
      int col = (w * 2 + c) * 16 + l15;
      float b2 = cb2[col], w3 = cw3[col];
#pragma unroll
      for (int r = 0; r < 4; ++r)
#pragma unroll
        for (int i = 0; i < 4; ++i)
          pr[r][i] += fmaxf(ac2[r][c][i] + b2, 0.f) * w3;
    }
#pragma unroll
    for (int m = 1; m <= 8; m <<= 1)
#pragma unroll
      for (int r = 0; r < 4; ++r)
#pragma unroll
        for (int i = 0; i < 4; ++i) pr[r][i] += __shfl_xor(pr[r][i], m, 64);
    if (l15 == 0) {
#pragma unroll
      for (int r = 0; r < 4; ++r)
#pragma unroll
        for (int i = 0; i < 4; ++i) redw[w * 64 + r * 16 + q * 4 + i] = pr[r][i];
    }
    __syncthreads();
    if (t < 64) {
      float s = redw[t] + redw[64 + t] + redw[128 + t] + redw[192 + t] + cb3[0];
      p_all[m0 + t] = expf(s);  // raw exp: scores O(1); identical to softmax after /sum
    }
    __syncthreads();

    // ---- matched accumulation (exact fp32 L re-read, register accumulators)
#pragma unroll 8
    for (int m = 0; m < 64; ++m) {
      float pm = p_all[m0 + m];
      const float* Lr = Lbn + (size_t)(m0 + m) * D_;
      mac0 += pm * Lr[t];
      mac1 += pm * Lr[t + 256];
      if (t < 12) mac2 += pm * Lr[t + 512];
    }
  }  // mtile

  // ---- softmax denominator via wave-0 shuffle reduce
  if (t < 64) {
    float v = p_all[t] + p_all[t + 64] + p_all[t + 128] + p_all[t + 192];
#pragma unroll
    for (int m = 1; m <= 32; m <<= 1) v += __shfl_xor(v, m, 64);
    if (t == 0) sS = 1.f / v;
  }
  __syncthreads();
  float invS = sS;
  out[CW_OFF + bn * 256 + t] = p_all[t] * invS;
  m_s[t] = mac0 * invS;
  m_s[t + 256] = mac1 * invS;
  if (t < 12) m_s[t + 512] = mac2 * invS;
  __syncthreads();

  // ---- overlap MLP partials on ALL 256 threads (2-way d-split), tgt_matched partials (t<96)
  {
    int o = t & 127, half = t >> 7;
    float a = 0.f;
#pragma unroll 4
    for (int dd = 0; dd < 262; ++dd) {
      int d = half * 262 + dd;
      a += m_s[d] * ow1[d * 128 + o];
    }
    ovp[t] = a;
  }
  if (t < 96) {
    int c = t % 3, g = t / 3;
    float s = 0.f;
#pragma unroll
    for (int m = 0; m < 8; ++m) s += p_all[g * 8 + m] * tgt[((b * 256) + g * 8 + m) * 3 + c];
    redw[t] = s;
  }
  __syncthreads();
  if (t < 128) o1s[t] = fmaxf(ovp[t] + ovp[t + 128] + ob1[t], 0.f) * ow2[t];
  __syncthreads();
  if (t < 64) {
    float v = o1s[t] + o1s[t + 64];
#pragma unroll
    for (int m = 1; m <= 32; m <<= 1) v += __shfl_xor(v, m, 64);
    if (t == 0) out[OV_OFF + bn] = 1.f / (1.f + expf(-(v + ob2[0])));
  }
  if (t < 3) {
    float s = 0.f;
    for (int g = 0; g < 32; ++g) s += redw[g * 3 + t];
    tgtm[bn * 3 + t] = s * invS;
  }
}

// ---------------- finalize: per-batch Kabsch via fp64 Jacobi SVD + Shepperd quaternion
__global__ __launch_bounds__(256) void finalize_kernel(const float* __restrict__ src,
                                                       const float* __restrict__ tgtm,
                                                       float* __restrict__ out) {
  int b = blockIdx.x, t = threadIdx.x;
  __shared__ float red[256];

  auto bsum = [&](float v) -> float {
    red[t] = v;
    __syncthreads();
    for (int s = 128; s > 0; s >>= 1) {
      if (t < s) red[t] += red[t + s];
      __syncthreads();
    }
    float r = red[0];
    __syncthreads();
    return r;
  };

  float wv = out[OV_OFF + b * 256 + t];
  float Sw = bsum(wv);
  float wn = wv / fmaxf(Sw, 1e-8f);
  float sc[3], tm[3];
#pragma unroll
  for (int c = 0; c < 3; ++c) {
    sc[c] = src[(b * 256 + t) * 3 + c];
    tm[c] = tgtm[(b * 256 + t) * 3 + c];
  }
  float sb[3], tb[3];
#pragma unroll
  for (int c = 0; c < 3; ++c) sb[c] = bsum(wn * sc[c]);
#pragma unroll
  for (int c = 0; c < 3; ++c) tb[c] = bsum(wn * tm[c]);
  float Hv[9];
#pragma unroll
  for (int c = 0; c < 3; ++c)
#pragma unroll
    for (int d = 0; d < 3; ++d)
      Hv[c * 3 + d] = bsum((sc[c] - sb[c]) * wn * (tm[d] - tb[d]));

  if (t == 0) {
    double H[3][3];
    for (int i = 0; i < 3; ++i)
      for (int j = 0; j < 3; ++j) H[i][j] = (double)Hv[i * 3 + j];
    // A = H^T H ; Jacobi eigendecomposition A = V diag V^T
    double A[3][3], V[3][3] = {{1, 0, 0}, {0, 1, 0}, {0, 0, 1}};
    for (int i = 0; i < 3; ++i)
      for (int j = 0; j < 3; ++j) {
        double s = 0;
        for (int k = 0; k < 3; ++k) s += H[k][i] * H[k][j];
        A[i][j] = s;
      }
    const int PQ[3][2] = {{0, 1}, {0, 2}, {1, 2}};
    for (int sweep = 0; sweep < 30; ++sweep)
      for (int r = 0; r < 3; ++r) {
        int p = PQ[r][0], qq = PQ[r][1];
        double apq = A[p][qq];
        if (fabs(apq) < 1e-300) continue;
        double tau = (A[qq][qq] - A[p][p]) / (2.0 * apq);
        double tt = (tau >= 0 ? 1.0 : -1.0) / (fabs(tau) + sqrt(1.0 + tau * tau));
        double cc = 1.0 / sqrt(1.0 + tt * tt), ss = tt * cc;
        for (int k = 0; k < 3; ++k) {
          double akp = A[k][p], akq = A[k][qq];
          A[k][p] = cc * akp - ss * akq;
          A[k][qq] = ss * akp + cc * akq;
        }
        for (int k = 0; k < 3; ++k) {
          double apk = A[p][k], aqk = A[qq][k];
          A[p][k] = cc * apk - ss * aqk;
          A[qq][k] = ss * apk + cc * aqk;
        }
        for (int k = 0; k < 3; ++k) {
          double vkp = V[k][p], vkq = V[k][qq];
          V[k][p] = cc * vkp - ss * vkq;
          V[k][qq] = ss * vkp + cc * vkq;
        }
      }
    // sort eigenvalues descending
    int idx[3] = {0, 1, 2};
    for (int i = 0; i < 2; ++i)
      for (int j = i + 1; j < 3; ++j)
        if (A[idx[j]][idx[j]] > A[idx[i]][idx[i]]) { int tmp = idx[i]; idx[i] = idx[j]; idx[j] = tmp; }
    double v0[3], v1[3], v2[3];
    for (int k = 0; k < 3; ++k) {
      v0[k] = V[k][idx[0]];
      v1[k] = V[k][idx[1]];
      v2[k] = V[k][idx[2]];
    }
    // U columns: u0 = Hv0/|..|, u1 orthonormalized, u2 = u0 x u1 (det-fix absorbs sign)
    double u0[3], u1[3], u2[3];
    for (int j = 0; j < 3; ++j) {
      u0[j] = H[j][0] * v0[0] + H[j][1] * v0[1] + H[j][2] * v0[2];
      u1[j] = H[j][0] * v1[0] + H[j][1] * v1[1] + H[j][2] * v1[2];
    }
    double n0 = sqrt(u0[0] * u0[0] + u0[1] * u0[1] + u0[2] * u0[2]);
    n0 = (n0 > 1e-300) ? n0 : 1e-300;
    for (int j = 0; j < 3; ++j) u0[j] /= n0;
    double d01 = u0[0] * u1[0] + u0[1] * u1[1] + u0[2] * u1[2];
    for (int j = 0; j < 3; ++j) u1[j] -= d01 * u0[j];
    double n1 = sqrt(u1[0] * u1[0] + u1[1] * u1[1] + u1[2] * u1[2]);
    n1 = (n1 > 1e-300) ? n1 : 1e-300;
    for (int j = 0; j < 3; ++j) u1[j] /= n1;
    u2[0] = u0[1] * u1[2] - u0[2] * u1[1];
    u2[1] = u0[2] * u1[0] - u0[0] * u1[2];
    u2[2] = u0[0] * u1[1] - u0[1] * u1[0];
    // R_raw = V U^T ; det sign ; R
    double Rr[3][3];
    for (int i = 0; i < 3; ++i)
      for (int j = 0; j < 3; ++j)
        Rr[i][j] = v0[i] * u0[j] + v1[i] * u1[j] + v2[i] * u2[j];
    double det = Rr[0][0] * (Rr[1][1] * Rr[2][2] - Rr[1][2] * Rr[2][1]) -
                 Rr[0][1] * (Rr[1][0] * Rr[2][2] - Rr[1][2] * Rr[2][0]) +
                 Rr[0][2] * (Rr[1][0] * Rr[2][1] - Rr[1][1] * Rr[2][0]);
    double sg = (det >= 0) ? 1.0 : -1.0;
    double R[3][3];
    for (int i = 0; i < 3; ++i)
      for (int j = 0; j < 3; ++j)
        R[i][j] = v0[i] * u0[j] + v1[i] * u1[j] + sg * v2[i] * u2[j];
    // translation = tgt_bar - R src_bar
    double trv[3];
    for (int i = 0; i < 3; ++i)
      trv[i] = (double)tb[i] - (R[i][0] * sb[0] + R[i][1] * sb[1] + R[i][2] * sb[2]);
    // Shepperd quaternion [x,y,z,w], branch structure identical to reference
    double qv[4];
    double tr = R[0][0] + R[1][1] + R[2][2];
    if (tr > 0) {
      double S = sqrt(fmax(tr + 1.0, 1e-10)) * 2.0;
      qv[0] = (R[2][1] - R[1][2]) / S;
      qv[1] = (R[0][2] - R[2][0]) / S;
      qv[2] = (R[1][0] - R[0][1]) / S;
      qv[3] = 0.25 * S;
    } else if (R[0][0] > R[1][1] && R[0][0] > R[2][2]) {
      double S = sqrt(fmax(1.0 + R[0][0] - R[1][1] - R[2][2], 1e-10)) * 2.0;
      qv[0] = 0.25 * S;
      qv[1] = (R[0][1] + R[1][0]) / S;
      qv[2] = (R[0][2] + R[2][0]) / S;
      qv[3] = (R[2][1] - R[1][2]) / S;
    } else if (R[1][1] > R[2][2]) {
      double S = sqrt(fmax(1.0 + R[1][1] - R[0][0] - R[2][2], 1e-10)) * 2.0;
      qv[0] = (R[0][1] + R[1][0]) / S;
      qv[1] = 0.25 * S;
      qv[2] = (R[1][2] + R[2][1]) / S;
      qv[3] = (R[0][2] - R[2][0]) / S;
    } else {
      double S = sqrt(fmax(1.0 + R[2][2] - R[0][0] - R[1][1], 1e-10)) * 2.0;
      qv[0] = (R[0][2] + R[2][0]) / S;
      qv[1] = (R[1][2] + R[2][1]) / S;
      qv[2] = 0.25 * S;
      qv[3] = (R[1][0] - R[0][1]) / S;
    }
    double qn = sqrt(qv[0] * qv[0] + qv[1] * qv[1] + qv[2] * qv[2] + qv[3] * qv[3]);
    qn = fmax(qn, 1e-12);
    for (int k = 0; k < 4; ++k) out[b * 4 + k] = (float)(qv[k] / qn);
    for (int i = 0; i < 3; ++i) out[16 + b * 3 + i] = (float)trv[i];
    for (int i = 0; i < 3; ++i)
      for (int j = 0; j < 3; ++j) out[28 + b * 9 + i * 3 + j] = (float)R[i][j];
  }
}

extern "C" void kernel_launch(void* const* d_in, const int* in_sizes, int n_in,
                              void* d_out, int out_size, void* d_ws, size_t ws_size,
                              hipStream_t stream) {
  const float* L = (const float*)d_in[0];
  const float* src = (const float*)d_in[1];
  const float* tgt = (const float*)d_in[2];
  const float* cw1 = (const float*)d_in[3];
  const float* cb1 = (const float*)d_in[4];
  const float* cw2 = (const float*)d_in[5];
  const float* cb2 = (const float*)d_in[6];
  const float* cw3 = (const float*)d_in[7];
  const float* cb3 = (const float*)d_in[8];
  const float* ow1 = (const float*)d_in[9];
  const float* ob1 = (const float*)d_in[10];
  const float* ow2 = (const float*)d_in[11];
  const float* ob2 = (const float*)d_in[12];
  float* out = (float*)d_out;

  // ws layout (~700 KB): W1 hi/lo frags, W2 hi/lo frags, tgt_matched[B,N,3]
  char* ws = (char*)d_ws;
  short* w1h = (short*)(ws);
  short* w1l = (short*)(ws + 278528);
  short* w2h = (short*)(ws + 557056);
  short* w2l = (short*)(ws + 622592);
  float* tgtm = (float*)(ws + 688128);

  hipLaunchKernelGGL(prep_kernel, dim3(84), dim3(256), 0, stream, cw1, cw2, w1h, w1l, w2h, w2l);
  hipLaunchKernelGGL(main_kernel, dim3(1024), dim3(256), 0, stream,
                     L, tgt, cb1, cb2, cw3, cb3, ow1, ob1, ow2, ob2,
                     (const short8*)w1h, (const short8*)w1l,
                     (const short8*)w2h, (const short8*)w2l, out, tgtm);
  hipLaunchKernelGGL(finalize_kernel, dim3(4), dim3(256), 0, stream, src, tgtm, out);
}